// Round 1
// baseline (1435.730 us; speedup 1.0000x reference)
//
#include <hip/hip_runtime.h>
#include <cstddef>

#define B_SZ 8
#define N_PTS 1024
#define KNN_K 20
#define CAT_C 512
#define BN_EPS 1e-5f

// ---------------- transpose x (B,3,N) -> feat0 (B,N,3) ----------------
__global__ __launch_bounds__(256) void transpose_x(const float* __restrict__ x,
                                                   float* __restrict__ feat0) {
  int t = blockIdx.x * 256 + threadIdx.x;
  if (t >= B_SZ * 3 * N_PTS) return;
  int b = t / (3 * N_PTS);
  int r = t - b * 3 * N_PTS;
  int c = r / N_PTS;
  int n = r - c * N_PTS;
  feat0[((size_t)(b * N_PTS + n)) * 3 + c] = x[t];
}

// ---------------- KNN: one wave per row, iterative top-20 argmax ----------------
__global__ __launch_bounds__(256) void knn_kernel(const float* __restrict__ feat,
                                                  int C, int lda,
                                                  int* __restrict__ idxout) {
  __shared__ float xn_sh[4][128];
  int warp = threadIdx.x >> 6;
  int lane = threadIdx.x & 63;
  int row = blockIdx.x * 4 + warp;      // 0..8191
  int b = row >> 10, n = row & 1023;
  const float* base = feat + (size_t)b * N_PTS * lda;

  for (int c = lane; c < C; c += 64) xn_sh[warp][c] = base[(size_t)n * lda + c];
  __syncthreads();

  float vals[16];
  if ((C & 3) == 0) {
    int C4 = C >> 2;
    const float4* xn4 = (const float4*)&xn_sh[warp][0];
    for (int t = 0; t < 16; ++t) {
      int m = t * 64 + lane;
      const float4* xm4 = (const float4*)(base + (size_t)m * lda);
      float s = 0.f;
      for (int c4 = 0; c4 < C4; ++c4) {
        float4 xm = xm4[c4];
        float4 xn = xn4[c4];
        float d0 = xn.x - xm.x, d1 = xn.y - xm.y, d2 = xn.z - xm.z, d3 = xn.w - xm.w;
        s = fmaf(d0, d0, s); s = fmaf(d1, d1, s); s = fmaf(d2, d2, s); s = fmaf(d3, d3, s);
      }
      vals[t] = -s;
    }
  } else {
    for (int t = 0; t < 16; ++t) {
      int m = t * 64 + lane;
      const float* xm = base + (size_t)m * lda;
      float s = 0.f;
      for (int c = 0; c < C; ++c) { float d = xn_sh[warp][c] - xm[c]; s = fmaf(d, d, s); }
      vals[t] = -s;
    }
  }

  for (int r = 0; r < KNN_K; ++r) {
    float bv = -3.4e38f;
    int bi = 0x7fffffff;
    #pragma unroll
    for (int t = 0; t < 16; ++t) {
      int m = t * 64 + lane;
      if (vals[t] > bv) { bv = vals[t]; bi = m; }   // t ascending keeps smallest m on ties
    }
    #pragma unroll
    for (int off = 32; off; off >>= 1) {
      float ov = __shfl_xor(bv, off, 64);
      int oi = __shfl_xor(bi, off, 64);
      if (ov > bv || (ov == bv && oi < bi)) { bv = ov; bi = oi; }
    }
    if ((bi & 63) == lane) vals[bi >> 6] = -3.4e38f;
    if (lane == 0) idxout[row * KNN_K + r] = bi;
  }
}

// ---------------- build combined weight Wc (K=C rows x N=2O cols): [w1-w2 | w2] ----------------
__global__ __launch_bounds__(256) void build_wc(const float* __restrict__ w, int C, int O,
                                                float* __restrict__ wc) {
  int t = blockIdx.x * 256 + threadIdx.x;
  int twoO = 2 * O;
  if (t >= C * twoO) return;
  int c = t / twoO, j = t - c * twoO;
  float v;
  if (j < O) v = w[j * (2 * C) + c] - w[j * (2 * C) + C + c];
  else       v = w[(j - O) * (2 * C) + C + c];
  wc[t] = v;
}

__global__ __launch_bounds__(256) void build_wc5(const float* __restrict__ w5,
                                                 float* __restrict__ wc) {
  int t = blockIdx.x * 256 + threadIdx.x;
  if (t >= 512 * 1024) return;
  int c = t >> 10, o = t & 1023;
  wc[t] = w5[o * 512 + c];
}

// ---------------- generic fp32 GEMM: C[M,N] = A[M,K](lda) * B[K,N] ----------------
__global__ __launch_bounds__(256) void gemm_kernel(const float* __restrict__ A, int lda,
                                                   const float* __restrict__ Bm,
                                                   float* __restrict__ Cm,
                                                   int M, int N, int K) {
  __shared__ float As[16][64];
  __shared__ float Bs[16][68];
  int tx = threadIdx.x & 15, ty = threadIdx.x >> 4;
  int bn0 = blockIdx.x * 64, bm0 = blockIdx.y * 64;
  float acc[4][4];
  #pragma unroll
  for (int i = 0; i < 4; ++i)
    #pragma unroll
    for (int j = 0; j < 4; ++j) acc[i][j] = 0.f;

  for (int k0 = 0; k0 < K; k0 += 16) {
    {
      int t = threadIdx.x;
      int m = t >> 2, kb = (t & 3) * 4;
      const float* ap = A + (size_t)(bm0 + m) * lda + k0 + kb;
      #pragma unroll
      for (int i = 0; i < 4; ++i) As[kb + i][m] = (k0 + kb + i < K) ? ap[i] : 0.f;
      int r = t >> 4, c4 = (t & 15) * 4;
      float4 bv = make_float4(0.f, 0.f, 0.f, 0.f);
      if (k0 + r < K) bv = *(const float4*)(Bm + (size_t)(k0 + r) * N + bn0 + c4);
      *(float4*)&Bs[r][c4] = bv;
    }
    __syncthreads();
    #pragma unroll
    for (int k = 0; k < 16; ++k) {
      float a0[4];
      #pragma unroll
      for (int i = 0; i < 4; ++i) a0[i] = As[k][ty * 4 + i];
      float4 bv = *(const float4*)&Bs[k][tx * 4];
      float b0[4] = {bv.x, bv.y, bv.z, bv.w};
      #pragma unroll
      for (int i = 0; i < 4; ++i)
        #pragma unroll
        for (int j = 0; j < 4; ++j) acc[i][j] = fmaf(a0[i], b0[j], acc[i][j]);
    }
    __syncthreads();
  }
  #pragma unroll
  for (int i = 0; i < 4; ++i) {
    float4 v = make_float4(acc[i][0], acc[i][1], acc[i][2], acc[i][3]);
    *(float4*)(Cm + (size_t)(bm0 + ty * 4 + i) * N + bn0 + tx * 4) = v;
  }
}

// ---------------- edge aggregation: h = a + y[idx]; max/min over k + channel sums ----------------
__global__ __launch_bounds__(256) void aggregate_kernel(const float* __restrict__ ay,
                                                        const int* __restrict__ idxb, int O,
                                                        float* __restrict__ mx,
                                                        float* __restrict__ mn,
                                                        float* __restrict__ sumsbin) {
  __shared__ float ls[2][256];
  for (int i = threadIdx.x; i < 512; i += 256) ((float*)ls)[i] = 0.f;
  __syncthreads();

  int warp = threadIdx.x >> 6, lane = threadIdx.x & 63;
  int pt = blockIdx.x * 4 + warp;   // 0..8191
  int b = pt >> 10;
  int twoO = 2 * O;
  int U = O >> 6;
  const float* ayrow = ay + (size_t)pt * twoO;

  float av[4], s1[4], s2[4], vmx[4], vmn[4];
  for (int u = 0; u < U; ++u) {
    av[u] = ayrow[u * 64 + lane];
    s1[u] = 0.f; s2[u] = 0.f; vmx[u] = -3.4e38f; vmn[u] = 3.4e38f;
  }
  const int* ip = idxb + pt * KNN_K;
  for (int k = 0; k < KNN_K; ++k) {
    int j = ip[k];
    const float* yrow = ay + (size_t)(b * N_PTS + j) * twoO + O;
    for (int u = 0; u < U; ++u) {
      float v = av[u] + yrow[u * 64 + lane];
      s1[u] += v; s2[u] = fmaf(v, v, s2[u]);
      vmx[u] = fmaxf(vmx[u], v); vmn[u] = fminf(vmn[u], v);
    }
  }
  for (int u = 0; u < U; ++u) {
    int o = u * 64 + lane;
    mx[(size_t)pt * O + o] = vmx[u];
    mn[(size_t)pt * O + o] = vmn[u];
    atomicAdd(&ls[0][o], s1[u]);
    atomicAdd(&ls[1][o], s2[u]);
  }
  __syncthreads();
  int bin = blockIdx.x & 63;
  float* gb = sumsbin + (size_t)bin * 512;
  for (int o = threadIdx.x; o < O; o += 256) {
    atomicAdd(&gb[o], ls[0][o]);
    atomicAdd(&gb[256 + o], ls[1][o]);
  }
}

__global__ __launch_bounds__(256) void reduce_bins(const float* __restrict__ sumsbin,
                                                   float* __restrict__ sums, int O) {
  int o = threadIdx.x;
  if (o >= O) return;
  float a = 0.f, c = 0.f;
  for (int bin = 0; bin < 64; ++bin) {
    a += sumsbin[bin * 512 + o];
    c += sumsbin[bin * 512 + 256 + o];
  }
  sums[o] = a;
  sums[256 + o] = c;
}

// ---------------- finalize edge layer: BN + relu on (max or min depending on sign) ----------------
__global__ __launch_bounds__(256) void finalize_edge(const float* __restrict__ mx,
                                                     const float* __restrict__ mn,
                                                     const float* __restrict__ sums,
                                                     const float* __restrict__ g,
                                                     const float* __restrict__ beta,
                                                     int oshift,
                                                     float* __restrict__ outseg,
                                                     float cnt_inv) {
  int tid = blockIdx.x * 256 + threadIdx.x;
  int pt = tid >> oshift;
  int o = tid & ((1 << oshift) - 1);
  float s1 = sums[o], s2 = sums[256 + o];
  float mean = s1 * cnt_inv;
  float var = s2 * cnt_inv - mean * mean;
  float rstd = rsqrtf(var + BN_EPS);
  float sc = g[o] * rstd;
  float sel = (sc >= 0.f) ? mx[tid] : mn[tid];
  float v = (sel - mean) * sc + beta[o];
  outseg[(size_t)pt * CAT_C + o] = fmaxf(v, 0.f);
}

// ---------------- layer 5 reductions ----------------
__global__ __launch_bounds__(256) void reduce5(const float* __restrict__ h5,
                                               float* __restrict__ h5mx,
                                               float* __restrict__ h5mn,
                                               float* __restrict__ sums5) {
  int oi = threadIdx.x & 63, ng = threadIdx.x >> 6;
  int o = blockIdx.x * 64 + oi;
  int b = blockIdx.y;
  float mx = -3.4e38f, mn = 3.4e38f, s1 = 0.f, s2 = 0.f;
  for (int n = ng; n < N_PTS; n += 4) {
    float v = h5[(size_t)(b * N_PTS + n) * 1024 + o];
    mx = fmaxf(mx, v); mn = fminf(mn, v);
    s1 += v; s2 = fmaf(v, v, s2);
  }
  __shared__ float red[4][4][64];
  red[ng][0][oi] = mx; red[ng][1][oi] = mn; red[ng][2][oi] = s1; red[ng][3][oi] = s2;
  __syncthreads();
  if (ng == 0) {
    #pragma unroll
    for (int gq = 1; gq < 4; ++gq) {
      mx = fmaxf(mx, red[gq][0][oi]);
      mn = fminf(mn, red[gq][1][oi]);
      s1 += red[gq][2][oi];
      s2 += red[gq][3][oi];
    }
    h5mx[b * 1024 + o] = mx;
    h5mn[b * 1024 + o] = mn;
    atomicAdd(&sums5[o], s1);
    atomicAdd(&sums5[1024 + o], s2);
  }
}

__global__ __launch_bounds__(256) void finalize5(const float* __restrict__ h5mx,
                                                 const float* __restrict__ h5mn,
                                                 const float* __restrict__ sums5,
                                                 const float* __restrict__ g,
                                                 const float* __restrict__ beta,
                                                 float* __restrict__ out,
                                                 float cnt_inv) {
  int tid = blockIdx.x * 256 + threadIdx.x;   // 0..8191
  int o = tid & 1023;
  float s1 = sums5[o], s2 = sums5[1024 + o];
  float mean = s1 * cnt_inv;
  float var = s2 * cnt_inv - mean * mean;
  float rstd = rsqrtf(var + BN_EPS);
  float sc = g[o] * rstd;
  float sel = (sc >= 0.f) ? h5mx[tid] : h5mn[tid];
  float v = (sel - mean) * sc + beta[o];
  out[tid] = fmaxf(v, 0.f);
}

extern "C" void kernel_launch(void* const* d_in, const int* in_sizes, int n_in,
                              void* d_out, int out_size, void* d_ws, size_t ws_size,
                              hipStream_t stream) {
  const float* x = (const float*)d_in[0];
  const float* w[5]  = {(const float*)d_in[1], (const float*)d_in[4], (const float*)d_in[7],
                        (const float*)d_in[10], (const float*)d_in[13]};
  const float* gg[5] = {(const float*)d_in[2], (const float*)d_in[5], (const float*)d_in[8],
                        (const float*)d_in[11], (const float*)d_in[14]};
  const float* bb[5] = {(const float*)d_in[3], (const float*)d_in[6], (const float*)d_in[9],
                        (const float*)d_in[12], (const float*)d_in[15]};
  float* out = (float*)d_out;

  float* W = (float*)d_ws;
  size_t off = 0;
  float* feat0   = W + off; off += (size_t)B_SZ * N_PTS * 3;
  float* catbuf  = W + off; off += (size_t)8192 * CAT_C;
  int*   idxbuf  = (int*)(W + off); off += (size_t)8192 * KNN_K;
  float* aybuf   = W + off; off += (size_t)8192 * 1024;
  float* mxbuf   = W + off; off += (size_t)8192 * 256;
  float* mnbuf   = W + off; off += (size_t)8192 * 256;
  float* wcbuf   = W + off; off += (size_t)512 * 1024;
  float* sumsbin = W + off; off += (size_t)64 * 512;
  float* sums    = W + off; off += 512;
  float* sums5   = W + off; off += 2048;
  float* h5mx    = W + off; off += 8192;
  float* h5mn    = W + off; off += 8192;

  transpose_x<<<(B_SZ * 3 * N_PTS + 255) / 256, 256, 0, stream>>>(x, feat0);

  const int Cs[4] = {3, 64, 64, 128};
  const int Os[4] = {64, 64, 128, 256};
  const int osh[4] = {6, 6, 7, 8};
  const int segin[4] = {0, 0, 64, 128};
  const int segout[4] = {0, 64, 128, 256};

  for (int l = 0; l < 4; ++l) {
    int C = Cs[l], O = Os[l], twoO = 2 * O;
    const float* featin = (l == 0) ? feat0 : (catbuf + segin[l]);
    int lda = (l == 0) ? 3 : CAT_C;

    knn_kernel<<<2048, 256, 0, stream>>>(featin, C, lda, idxbuf);
    build_wc<<<(C * twoO + 255) / 256, 256, 0, stream>>>(w[l], C, O, wcbuf);
    gemm_kernel<<<dim3(twoO / 64, 8192 / 64), 256, 0, stream>>>(featin, lda, wcbuf, aybuf,
                                                                8192, twoO, C);
    hipMemsetAsync(sumsbin, 0, (size_t)64 * 512 * sizeof(float), stream);
    aggregate_kernel<<<2048, 256, 0, stream>>>(aybuf, idxbuf, O, mxbuf, mnbuf, sumsbin);
    reduce_bins<<<1, 256, 0, stream>>>(sumsbin, sums, O);
    finalize_edge<<<(8192 * O) / 256, 256, 0, stream>>>(mxbuf, mnbuf, sums, gg[l], bb[l],
                                                        osh[l], catbuf + segout[l],
                                                        1.0f / (8192.0f * KNN_K));
  }

  // layer 5: h5 = w5 * cat, BN over (b,n), relu, max over n
  build_wc5<<<(512 * 1024 + 255) / 256, 256, 0, stream>>>(w[4], wcbuf);
  gemm_kernel<<<dim3(1024 / 64, 8192 / 64), 256, 0, stream>>>(catbuf, CAT_C, wcbuf, aybuf,
                                                              8192, 1024, 512);
  hipMemsetAsync(sums5, 0, 2048 * sizeof(float), stream);
  reduce5<<<dim3(16, 8), 256, 0, stream>>>(aybuf, h5mx, h5mn, sums5);
  finalize5<<<8192 / 256, 256, 0, stream>>>(h5mx, h5mn, sums5, gg[4], bb[4], out,
                                            1.0f / 8192.0f);
}

// Round 2
// 778.076 us; speedup vs baseline: 1.8452x; 1.8452x over previous
//
#include <hip/hip_runtime.h>
#include <cstddef>

#define B_SZ 8
#define N_PTS 1024
#define KNN_K 20
#define CAT_C 512
#define BN_EPS 1e-5f

// ---------------- transpose x (B,3,N) -> feat0 (B,N,3) ----------------
__global__ __launch_bounds__(256) void transpose_x(const float* __restrict__ x,
                                                   float* __restrict__ feat0) {
  int t = blockIdx.x * 256 + threadIdx.x;
  if (t >= B_SZ * 3 * N_PTS) return;
  int b = t / (3 * N_PTS);
  int r = t - b * 3 * N_PTS;
  int c = r / N_PTS;
  int n = r - c * N_PTS;
  feat0[((size_t)(b * N_PTS + n)) * 3 + c] = x[t];
}

// ---------------- squared norms per point ----------------
__global__ __launch_bounds__(256) void xnorm_kernel(const float* __restrict__ feat, int lda,
                                                    int C, float* __restrict__ x2) {
  int p = blockIdx.x * 256 + threadIdx.x;
  if (p >= 8192) return;
  const float* r = feat + (size_t)p * lda;
  float s = 0.f;
  if ((C & 3) == 0) {
    for (int c = 0; c < C; c += 4) {
      float4 v = *(const float4*)(r + c);
      s = fmaf(v.x, v.x, s); s = fmaf(v.y, v.y, s);
      s = fmaf(v.z, v.z, s); s = fmaf(v.w, v.w, s);
    }
  } else {
    for (int c = 0; c < C; ++c) s = fmaf(r[c], r[c], s);
  }
  x2[p] = s;
}

// ---------------- distance GEMM: pd[b,n,m] = (2*x_n.x_m - x2n) - x2m ----------------
__global__ __launch_bounds__(256) void dist_gemm(const float* __restrict__ feat, int lda, int K,
                                                 const float* __restrict__ x2,
                                                 float* __restrict__ D) {
  int b = blockIdx.z;
  const float* A = feat + (size_t)b * N_PTS * lda;
  const float* x2b = x2 + b * N_PTS;
  __shared__ float As[16][64];
  __shared__ float Bs[16][68];
  int tx = threadIdx.x & 15, ty = threadIdx.x >> 4;
  int bn0 = blockIdx.x * 64, bm0 = blockIdx.y * 64;
  float acc[4][4];
  #pragma unroll
  for (int i = 0; i < 4; ++i)
    #pragma unroll
    for (int j = 0; j < 4; ++j) acc[i][j] = 0.f;

  for (int k0 = 0; k0 < K; k0 += 16) {
    int t = threadIdx.x;
    int m = t >> 2, kb = (t & 3) * 4;
    const float* ap = A + (size_t)(bm0 + m) * lda + k0 + kb;
    #pragma unroll
    for (int i = 0; i < 4; ++i) As[kb + i][m] = (k0 + kb + i < K) ? ap[i] : 0.f;
    const float* bp = A + (size_t)(bn0 + m) * lda + k0 + kb;
    #pragma unroll
    for (int i = 0; i < 4; ++i) Bs[kb + i][m] = (k0 + kb + i < K) ? bp[i] : 0.f;
    __syncthreads();
    #pragma unroll
    for (int k = 0; k < 16; ++k) {
      float a0[4];
      #pragma unroll
      for (int i = 0; i < 4; ++i) a0[i] = As[k][ty * 4 + i];
      float4 bv = *(const float4*)&Bs[k][tx * 4];
      float b0[4] = {bv.x, bv.y, bv.z, bv.w};
      #pragma unroll
      for (int i = 0; i < 4; ++i)
        #pragma unroll
        for (int j = 0; j < 4; ++j) acc[i][j] = fmaf(a0[i], b0[j], acc[i][j]);
    }
    __syncthreads();
  }
  float x2c[4];
  #pragma unroll
  for (int j = 0; j < 4; ++j) x2c[j] = x2b[bn0 + tx * 4 + j];
  #pragma unroll
  for (int i = 0; i < 4; ++i) {
    float x2r = x2b[bm0 + ty * 4 + i];
    float4 v;
    v.x = (2.f * acc[i][0] - x2r) - x2c[0];
    v.y = (2.f * acc[i][1] - x2r) - x2c[1];
    v.z = (2.f * acc[i][2] - x2r) - x2c[2];
    v.w = (2.f * acc[i][3] - x2r) - x2c[3];
    *(float4*)(D + ((size_t)b * N_PTS + bm0 + ty * 4 + i) * 1024 + bn0 + tx * 4) = v;
  }
}

// ---------------- top-20 selection: one wave per row ----------------
__global__ __launch_bounds__(256) void knn_select(const float* __restrict__ D,
                                                  int* __restrict__ idxout) {
  int warp = threadIdx.x >> 6, lane = threadIdx.x & 63;
  int row = blockIdx.x * 4 + warp;    // 0..8191
  const float* drow = D + (size_t)row * 1024;

  float vals[16];
  #pragma unroll
  for (int t4 = 0; t4 < 4; ++t4) {
    float4 dv = *(const float4*)(drow + lane * 16 + t4 * 4);
    vals[t4 * 4 + 0] = dv.x;
    vals[t4 * 4 + 1] = dv.y;
    vals[t4 * 4 + 2] = dv.z;
    vals[t4 * 4 + 3] = dv.w;
  }

  for (int r = 0; r < KNN_K; ++r) {
    float bv = -3.4e38f;
    int bi = 0x7fffffff;
    #pragma unroll
    for (int t = 0; t < 16; ++t) {
      // t ascending => index ascending within lane; strict > keeps smallest index on tie
      if (vals[t] > bv) { bv = vals[t]; bi = lane * 16 + t; }
    }
    #pragma unroll
    for (int off = 32; off; off >>= 1) {
      float ov = __shfl_xor(bv, off, 64);
      int oi = __shfl_xor(bi, off, 64);
      if (ov > bv || (ov == bv && oi < bi)) { bv = ov; bi = oi; }
    }
    if ((bi >> 4) == lane) vals[bi & 15] = -3.4e38f;
    if (lane == 0) idxout[row * KNN_K + r] = bi;
  }
}

// ---------------- build combined weight Wc (K=C rows x N=2O cols): [w1-w2 | w2] ----------------
__global__ __launch_bounds__(256) void build_wc(const float* __restrict__ w, int C, int O,
                                                float* __restrict__ wc) {
  int t = blockIdx.x * 256 + threadIdx.x;
  int twoO = 2 * O;
  if (t >= C * twoO) return;
  int c = t / twoO, j = t - c * twoO;
  float v;
  if (j < O) v = w[j * (2 * C) + c] - w[j * (2 * C) + C + c];
  else       v = w[(j - O) * (2 * C) + C + c];
  wc[t] = v;
}

__global__ __launch_bounds__(256) void build_wc5(const float* __restrict__ w5,
                                                 float* __restrict__ wc) {
  int t = blockIdx.x * 256 + threadIdx.x;
  if (t >= 512 * 1024) return;
  int c = t >> 10, o = t & 1023;
  wc[t] = w5[o * 512 + c];
}

// ---------------- generic fp32 GEMM: C[M,N] = A[M,K](lda) * B[K,N] ----------------
__global__ __launch_bounds__(256) void gemm_kernel(const float* __restrict__ A, int lda,
                                                   const float* __restrict__ Bm,
                                                   float* __restrict__ Cm,
                                                   int M, int N, int K) {
  __shared__ float As[16][64];
  __shared__ float Bs[16][68];
  int tx = threadIdx.x & 15, ty = threadIdx.x >> 4;
  int bn0 = blockIdx.x * 64, bm0 = blockIdx.y * 64;
  float acc[4][4];
  #pragma unroll
  for (int i = 0; i < 4; ++i)
    #pragma unroll
    for (int j = 0; j < 4; ++j) acc[i][j] = 0.f;

  for (int k0 = 0; k0 < K; k0 += 16) {
    {
      int t = threadIdx.x;
      int m = t >> 2, kb = (t & 3) * 4;
      const float* ap = A + (size_t)(bm0 + m) * lda + k0 + kb;
      #pragma unroll
      for (int i = 0; i < 4; ++i) As[kb + i][m] = (k0 + kb + i < K) ? ap[i] : 0.f;
      int r = t >> 4, c4 = (t & 15) * 4;
      float4 bv = make_float4(0.f, 0.f, 0.f, 0.f);
      if (k0 + r < K) bv = *(const float4*)(Bm + (size_t)(k0 + r) * N + bn0 + c4);
      *(float4*)&Bs[r][c4] = bv;
    }
    __syncthreads();
    #pragma unroll
    for (int k = 0; k < 16; ++k) {
      float a0[4];
      #pragma unroll
      for (int i = 0; i < 4; ++i) a0[i] = As[k][ty * 4 + i];
      float4 bv = *(const float4*)&Bs[k][tx * 4];
      float b0[4] = {bv.x, bv.y, bv.z, bv.w};
      #pragma unroll
      for (int i = 0; i < 4; ++i)
        #pragma unroll
        for (int j = 0; j < 4; ++j) acc[i][j] = fmaf(a0[i], b0[j], acc[i][j]);
    }
    __syncthreads();
  }
  #pragma unroll
  for (int i = 0; i < 4; ++i) {
    float4 v = make_float4(acc[i][0], acc[i][1], acc[i][2], acc[i][3]);
    *(float4*)(Cm + (size_t)(bm0 + ty * 4 + i) * N + bn0 + tx * 4) = v;
  }
}

// ---------------- edge aggregation: h = a + y[idx]; max/min over k + channel sums ----------------
__global__ __launch_bounds__(256) void aggregate_kernel(const float* __restrict__ ay,
                                                        const int* __restrict__ idxb, int O,
                                                        float* __restrict__ mx,
                                                        float* __restrict__ mn,
                                                        float* __restrict__ sumsbin) {
  __shared__ float ls[2][256];
  for (int i = threadIdx.x; i < 512; i += 256) ((float*)ls)[i] = 0.f;
  __syncthreads();

  int warp = threadIdx.x >> 6, lane = threadIdx.x & 63;
  int pt = blockIdx.x * 4 + warp;   // 0..8191
  int b = pt >> 10;
  int twoO = 2 * O;
  int U = O >> 6;
  const float* ayrow = ay + (size_t)pt * twoO;

  float av[4], s1[4], s2[4], vmx[4], vmn[4];
  for (int u = 0; u < U; ++u) {
    av[u] = ayrow[u * 64 + lane];
    s1[u] = 0.f; s2[u] = 0.f; vmx[u] = -3.4e38f; vmn[u] = 3.4e38f;
  }
  const int* ip = idxb + pt * KNN_K;
  for (int k = 0; k < KNN_K; ++k) {
    int j = ip[k];
    const float* yrow = ay + (size_t)(b * N_PTS + j) * twoO + O;
    for (int u = 0; u < U; ++u) {
      float v = av[u] + yrow[u * 64 + lane];
      s1[u] += v; s2[u] = fmaf(v, v, s2[u]);
      vmx[u] = fmaxf(vmx[u], v); vmn[u] = fminf(vmn[u], v);
    }
  }
  for (int u = 0; u < U; ++u) {
    int o = u * 64 + lane;
    mx[(size_t)pt * O + o] = vmx[u];
    mn[(size_t)pt * O + o] = vmn[u];
    atomicAdd(&ls[0][o], s1[u]);
    atomicAdd(&ls[1][o], s2[u]);
  }
  __syncthreads();
  int bin = blockIdx.x & 63;
  float* gb = sumsbin + (size_t)bin * 512;
  for (int o = threadIdx.x; o < O; o += 256) {
    atomicAdd(&gb[o], ls[0][o]);
    atomicAdd(&gb[256 + o], ls[1][o]);
  }
}

__global__ __launch_bounds__(256) void reduce_bins(const float* __restrict__ sumsbin,
                                                   float* __restrict__ sums, int O) {
  int o = threadIdx.x;
  if (o >= O) return;
  float a = 0.f, c = 0.f;
  for (int bin = 0; bin < 64; ++bin) {
    a += sumsbin[bin * 512 + o];
    c += sumsbin[bin * 512 + 256 + o];
  }
  sums[o] = a;
  sums[256 + o] = c;
}

// ---------------- finalize edge layer: BN + relu on (max or min depending on sign) ----------------
__global__ __launch_bounds__(256) void finalize_edge(const float* __restrict__ mx,
                                                     const float* __restrict__ mn,
                                                     const float* __restrict__ sums,
                                                     const float* __restrict__ g,
                                                     const float* __restrict__ beta,
                                                     int oshift,
                                                     float* __restrict__ outseg,
                                                     float cnt_inv) {
  int tid = blockIdx.x * 256 + threadIdx.x;
  int pt = tid >> oshift;
  int o = tid & ((1 << oshift) - 1);
  float s1 = sums[o], s2 = sums[256 + o];
  float mean = s1 * cnt_inv;
  float var = s2 * cnt_inv - mean * mean;
  float rstd = rsqrtf(var + BN_EPS);
  float sc = g[o] * rstd;
  float sel = (sc >= 0.f) ? mx[tid] : mn[tid];
  float v = (sel - mean) * sc + beta[o];
  outseg[(size_t)pt * CAT_C + o] = fmaxf(v, 0.f);
}

// ---------------- layer 5 reductions ----------------
__global__ __launch_bounds__(256) void reduce5(const float* __restrict__ h5,
                                               float* __restrict__ h5mx,
                                               float* __restrict__ h5mn,
                                               float* __restrict__ sums5) {
  int oi = threadIdx.x & 63, ng = threadIdx.x >> 6;
  int o = blockIdx.x * 64 + oi;
  int b = blockIdx.y;
  float mx = -3.4e38f, mn = 3.4e38f, s1 = 0.f, s2 = 0.f;
  for (int n = ng; n < N_PTS; n += 4) {
    float v = h5[(size_t)(b * N_PTS + n) * 1024 + o];
    mx = fmaxf(mx, v); mn = fminf(mn, v);
    s1 += v; s2 = fmaf(v, v, s2);
  }
  __shared__ float red[4][4][64];
  red[ng][0][oi] = mx; red[ng][1][oi] = mn; red[ng][2][oi] = s1; red[ng][3][oi] = s2;
  __syncthreads();
  if (ng == 0) {
    #pragma unroll
    for (int gq = 1; gq < 4; ++gq) {
      mx = fmaxf(mx, red[gq][0][oi]);
      mn = fminf(mn, red[gq][1][oi]);
      s1 += red[gq][2][oi];
      s2 += red[gq][3][oi];
    }
    h5mx[b * 1024 + o] = mx;
    h5mn[b * 1024 + o] = mn;
    atomicAdd(&sums5[o], s1);
    atomicAdd(&sums5[1024 + o], s2);
  }
}

__global__ __launch_bounds__(256) void finalize5(const float* __restrict__ h5mx,
                                                 const float* __restrict__ h5mn,
                                                 const float* __restrict__ sums5,
                                                 const float* __restrict__ g,
                                                 const float* __restrict__ beta,
                                                 float* __restrict__ out,
                                                 float cnt_inv) {
  int tid = blockIdx.x * 256 + threadIdx.x;   // 0..8191
  int o = tid & 1023;
  float s1 = sums5[o], s2 = sums5[1024 + o];
  float mean = s1 * cnt_inv;
  float var = s2 * cnt_inv - mean * mean;
  float rstd = rsqrtf(var + BN_EPS);
  float sc = g[o] * rstd;
  float sel = (sc >= 0.f) ? h5mx[tid] : h5mn[tid];
  float v = (sel - mean) * sc + beta[o];
  out[tid] = fmaxf(v, 0.f);
}

extern "C" void kernel_launch(void* const* d_in, const int* in_sizes, int n_in,
                              void* d_out, int out_size, void* d_ws, size_t ws_size,
                              hipStream_t stream) {
  const float* x = (const float*)d_in[0];
  const float* w[5]  = {(const float*)d_in[1], (const float*)d_in[4], (const float*)d_in[7],
                        (const float*)d_in[10], (const float*)d_in[13]};
  const float* gg[5] = {(const float*)d_in[2], (const float*)d_in[5], (const float*)d_in[8],
                        (const float*)d_in[11], (const float*)d_in[14]};
  const float* bb[5] = {(const float*)d_in[3], (const float*)d_in[6], (const float*)d_in[9],
                        (const float*)d_in[12], (const float*)d_in[15]};
  float* out = (float*)d_out;

  float* W = (float*)d_ws;
  size_t off = 0;
  float* feat0   = W + off; off += (size_t)B_SZ * N_PTS * 3;
  float* catbuf  = W + off; off += (size_t)8192 * CAT_C;
  int*   idxbuf  = (int*)(W + off); off += (size_t)8192 * KNN_K;
  float* aybuf   = W + off; off += (size_t)8192 * 1024;   // also aliased as distance matrix D
  float* mxbuf   = W + off; off += (size_t)8192 * 256;
  float* mnbuf   = W + off; off += (size_t)8192 * 256;
  float* wcbuf   = W + off; off += (size_t)512 * 1024;
  float* sumsbin = W + off; off += (size_t)64 * 512;
  float* sums    = W + off; off += 512;
  float* sums5   = W + off; off += 2048;
  float* h5mx    = W + off; off += 8192;
  float* h5mn    = W + off; off += 8192;
  float* x2buf   = W + off; off += 8192;

  float* Dbuf = aybuf;   // dead before/after knn per layer, same size (8M floats)

  transpose_x<<<(B_SZ * 3 * N_PTS + 255) / 256, 256, 0, stream>>>(x, feat0);

  const int Cs[4] = {3, 64, 64, 128};
  const int Os[4] = {64, 64, 128, 256};
  const int osh[4] = {6, 6, 7, 8};
  const int segin[4] = {0, 0, 64, 128};
  const int segout[4] = {0, 64, 128, 256};

  for (int l = 0; l < 4; ++l) {
    int C = Cs[l], O = Os[l], twoO = 2 * O;
    const float* featin = (l == 0) ? feat0 : (catbuf + segin[l]);
    int lda = (l == 0) ? 3 : CAT_C;

    xnorm_kernel<<<32, 256, 0, stream>>>(featin, lda, C, x2buf);
    dist_gemm<<<dim3(16, 16, 8), 256, 0, stream>>>(featin, lda, C, x2buf, Dbuf);
    knn_select<<<2048, 256, 0, stream>>>(Dbuf, idxbuf);

    build_wc<<<(C * twoO + 255) / 256, 256, 0, stream>>>(w[l], C, O, wcbuf);
    gemm_kernel<<<dim3(twoO / 64, 8192 / 64), 256, 0, stream>>>(featin, lda, wcbuf, aybuf,
                                                                8192, twoO, C);
    hipMemsetAsync(sumsbin, 0, (size_t)64 * 512 * sizeof(float), stream);
    aggregate_kernel<<<2048, 256, 0, stream>>>(aybuf, idxbuf, O, mxbuf, mnbuf, sumsbin);
    reduce_bins<<<1, 256, 0, stream>>>(sumsbin, sums, O);
    finalize_edge<<<(8192 * O) / 256, 256, 0, stream>>>(mxbuf, mnbuf, sums, gg[l], bb[l],
                                                        osh[l], catbuf + segout[l],
                                                        1.0f / (8192.0f * KNN_K));
  }

  // layer 5: h5 = w5 * cat, BN over (b,n), relu, max over n
  build_wc5<<<(512 * 1024 + 255) / 256, 256, 0, stream>>>(w[4], wcbuf);
  gemm_kernel<<<dim3(1024 / 64, 8192 / 64), 256, 0, stream>>>(catbuf, CAT_C, wcbuf, aybuf,
                                                              8192, 1024, 512);
  hipMemsetAsync(sums5, 0, 2048 * sizeof(float), stream);
  reduce5<<<dim3(16, 8), 256, 0, stream>>>(aybuf, h5mx, h5mn, sums5);
  finalize5<<<8192 / 256, 256, 0, stream>>>(h5mx, h5mn, sums5, gg[4], bb[4], out,
                                            1.0f / 8192.0f);
}

// Round 4
// 680.266 us; speedup vs baseline: 2.1105x; 1.1438x over previous
//
#include <hip/hip_runtime.h>
#include <cstddef>

#define B_SZ 8
#define N_PTS 1024
#define KNN_K 20
#define CAT_C 512
#define BN_EPS 1e-5f

typedef unsigned short u16;
typedef unsigned int u32;
typedef __bf16 bf16x8 __attribute__((ext_vector_type(8)));
typedef float f32x4 __attribute__((ext_vector_type(4)));

// ---------------- transpose x (B,3,N) -> feat0 (B,N,3) ----------------
__global__ __launch_bounds__(256) void transpose_x(const float* __restrict__ x,
                                                   float* __restrict__ feat0) {
  int t = blockIdx.x * 256 + threadIdx.x;
  if (t >= B_SZ * 3 * N_PTS) return;
  int b = t / (3 * N_PTS);
  int r = t - b * 3 * N_PTS;
  int c = r / N_PTS;
  int n = r - c * N_PTS;
  feat0[((size_t)(b * N_PTS + n)) * 3 + c] = x[t];
}

// ---------------- squared norms per point ----------------
__global__ __launch_bounds__(256) void xnorm_kernel(const float* __restrict__ feat, int lda,
                                                    int C, float* __restrict__ x2) {
  int p = blockIdx.x * 256 + threadIdx.x;
  if (p >= 8192) return;
  const float* r = feat + (size_t)p * lda;
  float s = 0.f;
  if ((C & 3) == 0) {
    for (int c = 0; c < C; c += 4) {
      float4 v = *(const float4*)(r + c);
      s = fmaf(v.x, v.x, s); s = fmaf(v.y, v.y, s);
      s = fmaf(v.z, v.z, s); s = fmaf(v.w, v.w, s);
    }
  } else {
    for (int c = 0; c < C; ++c) s = fmaf(r[c], r[c], s);
  }
  x2[p] = s;
}

// ---------------- distance GEMM: pd[b,n,m] = (2*x_n.x_m - x2n) - x2m (fp32) ----------------
__global__ __launch_bounds__(256) void dist_gemm(const float* __restrict__ feat, int lda, int K,
                                                 const float* __restrict__ x2,
                                                 float* __restrict__ D) {
  int b = blockIdx.z;
  const float* A = feat + (size_t)b * N_PTS * lda;
  const float* x2b = x2 + b * N_PTS;
  __shared__ float As[16][64];
  __shared__ float Bs[16][68];
  int tx = threadIdx.x & 15, ty = threadIdx.x >> 4;
  int bn0 = blockIdx.x * 64, bm0 = blockIdx.y * 64;
  float acc[4][4];
  #pragma unroll
  for (int i = 0; i < 4; ++i)
    #pragma unroll
    for (int j = 0; j < 4; ++j) acc[i][j] = 0.f;

  for (int k0 = 0; k0 < K; k0 += 16) {
    int t = threadIdx.x;
    int m = t >> 2, kb = (t & 3) * 4;
    const float* ap = A + (size_t)(bm0 + m) * lda + k0 + kb;
    #pragma unroll
    for (int i = 0; i < 4; ++i) As[kb + i][m] = (k0 + kb + i < K) ? ap[i] : 0.f;
    const float* bp = A + (size_t)(bn0 + m) * lda + k0 + kb;
    #pragma unroll
    for (int i = 0; i < 4; ++i) Bs[kb + i][m] = (k0 + kb + i < K) ? bp[i] : 0.f;
    __syncthreads();
    #pragma unroll
    for (int k = 0; k < 16; ++k) {
      float a0[4];
      #pragma unroll
      for (int i = 0; i < 4; ++i) a0[i] = As[k][ty * 4 + i];
      float4 bv = *(const float4*)&Bs[k][tx * 4];
      float b0[4] = {bv.x, bv.y, bv.z, bv.w};
      #pragma unroll
      for (int i = 0; i < 4; ++i)
        #pragma unroll
        for (int j = 0; j < 4; ++j) acc[i][j] = fmaf(a0[i], b0[j], acc[i][j]);
    }
    __syncthreads();
  }
  float x2c[4];
  #pragma unroll
  for (int j = 0; j < 4; ++j) x2c[j] = x2b[bn0 + tx * 4 + j];
  #pragma unroll
  for (int i = 0; i < 4; ++i) {
    float x2r = x2b[bm0 + ty * 4 + i];
    float4 v;
    v.x = (2.f * acc[i][0] - x2r) - x2c[0];
    v.y = (2.f * acc[i][1] - x2r) - x2c[1];
    v.z = (2.f * acc[i][2] - x2r) - x2c[2];
    v.w = (2.f * acc[i][3] - x2r) - x2c[3];
    *(float4*)(D + ((size_t)b * N_PTS + bm0 + ty * 4 + i) * 1024 + bn0 + tx * 4) = v;
  }
}

// ---------------- top-20 selection: one wave per row ----------------
__global__ __launch_bounds__(256) void knn_select(const float* __restrict__ D,
                                                  int* __restrict__ idxout) {
  int warp = threadIdx.x >> 6, lane = threadIdx.x & 63;
  int row = blockIdx.x * 4 + warp;    // 0..8191
  const float* drow = D + (size_t)row * 1024;

  float vals[16];
  #pragma unroll
  for (int t4 = 0; t4 < 4; ++t4) {
    float4 dv = *(const float4*)(drow + lane * 16 + t4 * 4);
    vals[t4 * 4 + 0] = dv.x;
    vals[t4 * 4 + 1] = dv.y;
    vals[t4 * 4 + 2] = dv.z;
    vals[t4 * 4 + 3] = dv.w;
  }

  for (int r = 0; r < KNN_K; ++r) {
    float bv = -3.4e38f;
    int bi = 0x7fffffff;
    #pragma unroll
    for (int t = 0; t < 16; ++t) {
      if (vals[t] > bv) { bv = vals[t]; bi = lane * 16 + t; }
    }
    #pragma unroll
    for (int off = 32; off; off >>= 1) {
      float ov = __shfl_xor(bv, off, 64);
      int oi = __shfl_xor(bi, off, 64);
      if (ov > bv || (ov == bv && oi < bi)) { bv = ov; bi = oi; }
    }
    if ((bi >> 4) == lane) vals[bi & 15] = -3.4e38f;
    if (lane == 0) idxout[row * KNN_K + r] = bi;
  }
}

// ---------------- build combined weight Wc (fp32): [w1-w2 | w2], K=C rows x 2O cols ----------------
__global__ __launch_bounds__(256) void build_wc(const float* __restrict__ w, int C, int O,
                                                float* __restrict__ wc) {
  int t = blockIdx.x * 256 + threadIdx.x;
  int twoO = 2 * O;
  if (t >= C * twoO) return;
  int c = t / twoO, j = t - c * twoO;
  float v;
  if (j < O) v = w[j * (2 * C) + c] - w[j * (2 * C) + C + c];
  else       v = w[(j - O) * (2 * C) + C + c];
  wc[t] = v;
}

// ---------------- fp32 GEMM (edge layers): C[M,N] = A[M,K](lda) * B[K,N] ----------------
__global__ __launch_bounds__(256) void gemm_kernel(const float* __restrict__ A, int lda,
                                                   const float* __restrict__ Bm,
                                                   float* __restrict__ Cm,
                                                   int M, int N, int K) {
  __shared__ float As[16][64];
  __shared__ float Bs[16][68];
  int tx = threadIdx.x & 15, ty = threadIdx.x >> 4;
  int bn0 = blockIdx.x * 64, bm0 = blockIdx.y * 64;
  float acc[4][4];
  #pragma unroll
  for (int i = 0; i < 4; ++i)
    #pragma unroll
    for (int j = 0; j < 4; ++j) acc[i][j] = 0.f;

  for (int k0 = 0; k0 < K; k0 += 16) {
    {
      int t = threadIdx.x;
      int m = t >> 2, kb = (t & 3) * 4;
      const float* ap = A + (size_t)(bm0 + m) * lda + k0 + kb;
      #pragma unroll
      for (int i = 0; i < 4; ++i) As[kb + i][m] = (k0 + kb + i < K) ? ap[i] : 0.f;
      int r = t >> 4, c4 = (t & 15) * 4;
      float4 bv = make_float4(0.f, 0.f, 0.f, 0.f);
      if (k0 + r < K) bv = *(const float4*)(Bm + (size_t)(k0 + r) * N + bn0 + c4);
      *(float4*)&Bs[r][c4] = bv;
    }
    __syncthreads();
    #pragma unroll
    for (int k = 0; k < 16; ++k) {
      float a0[4];
      #pragma unroll
      for (int i = 0; i < 4; ++i) a0[i] = As[k][ty * 4 + i];
      float4 bv = *(const float4*)&Bs[k][tx * 4];
      float b0[4] = {bv.x, bv.y, bv.z, bv.w};
      #pragma unroll
      for (int i = 0; i < 4; ++i)
        #pragma unroll
        for (int j = 0; j < 4; ++j) acc[i][j] = fmaf(a0[i], b0[j], acc[i][j]);
    }
    __syncthreads();
  }
  #pragma unroll
  for (int i = 0; i < 4; ++i) {
    float4 v = make_float4(acc[i][0], acc[i][1], acc[i][2], acc[i][3]);
    *(float4*)(Cm + (size_t)(bm0 + ty * 4 + i) * N + bn0 + tx * 4) = v;
  }
}

// ---------------- split fp32 -> bf16 hi/lo MFMA GEMM: C[M,N] = A[M,K] * Bt[N,K]^T ----------------
// Markidis split: A*B ~= Ah*Bh + Al*Bh + Ah*Bl (fp32 accumulate) -> ~fp32 accuracy.
// A fp32 row stride lda; Bt fp32 row stride ldb. K%64==0, M%128==0, N%128==0.
__device__ inline void split8(const float* __restrict__ p, bf16x8* hv, bf16x8* lv) {
  float4 a0 = *(const float4*)p, a1 = *(const float4*)(p + 4);
  float v[8] = {a0.x, a0.y, a0.z, a0.w, a1.x, a1.y, a1.z, a1.w};
  bf16x8 h, l;
  #pragma unroll
  for (int j = 0; j < 8; ++j) {
    __bf16 hj = (__bf16)v[j];
    h[j] = hj;
    l[j] = (__bf16)(v[j] - (float)hj);
  }
  *hv = h; *lv = l;
}

__global__ __launch_bounds__(256) void gemm_split(const float* __restrict__ A, int lda,
                                                  const float* __restrict__ Bt, int ldb,
                                                  float* __restrict__ C, int N, int K) {
  __shared__ u16 Ah[128 * 64];
  __shared__ u16 Al[128 * 64];
  __shared__ u16 Bh[128 * 64];
  __shared__ u16 Bl[128 * 64];
  int tid = threadIdx.x;
  int wave = tid >> 6, lane = tid & 63;
  int wr = wave >> 1, wc = wave & 1;
  int bn0 = blockIdx.x * 128, bm0 = blockIdx.y * 128;
  int lrow = lane & 15;
  int kgrp = lane >> 4;

  f32x4 acc[4][4];
  #pragma unroll
  for (int i = 0; i < 4; ++i)
    #pragma unroll
    for (int j = 0; j < 4; ++j) acc[i][j] = (f32x4){0.f, 0.f, 0.f, 0.f};

  for (int k0 = 0; k0 < K; k0 += 64) {
    // stage: per operand 128 rows x 64 fp32 -> hi/lo bf16 tiles (XOR-swizzled 16B slots)
    #pragma unroll
    for (int i = 0; i < 4; ++i) {
      int chunk = tid + i * 256;        // 0..1023
      int row = chunk >> 3;             // 0..127
      int cc = (chunk & 7) * 8;         // fp32 col 0,8,..,56
      int byte = row * 128 + ((cc * 2) ^ ((row & 7) << 4));
      bf16x8 h, l;
      split8(A + (size_t)(bm0 + row) * lda + k0 + cc, &h, &l);
      *(bf16x8*)((char*)Ah + byte) = h;
      *(bf16x8*)((char*)Al + byte) = l;
      split8(Bt + (size_t)(bn0 + row) * ldb + k0 + cc, &h, &l);
      *(bf16x8*)((char*)Bh + byte) = h;
      *(bf16x8*)((char*)Bl + byte) = l;
    }
    __syncthreads();
    #pragma unroll
    for (int kk = 0; kk < 64; kk += 32) {
      int kb = (kk + kgrp * 8) * 2;
      bf16x8 afh[4], afl[4], bfh[4], bfl[4];
      #pragma unroll
      for (int f = 0; f < 4; ++f) {
        int arow = wr * 64 + f * 16 + lrow;
        int abyte = arow * 128 + (kb ^ ((arow & 7) << 4));
        afh[f] = *(const bf16x8*)((const char*)Ah + abyte);
        afl[f] = *(const bf16x8*)((const char*)Al + abyte);
        int brow = wc * 64 + f * 16 + lrow;
        int bbyte = brow * 128 + (kb ^ ((brow & 7) << 4));
        bfh[f] = *(const bf16x8*)((const char*)Bh + bbyte);
        bfl[f] = *(const bf16x8*)((const char*)Bl + bbyte);
      }
      #pragma unroll
      for (int fm = 0; fm < 4; ++fm)
        #pragma unroll
        for (int fn = 0; fn < 4; ++fn) {
          acc[fm][fn] = __builtin_amdgcn_mfma_f32_16x16x32_bf16(afh[fm], bfh[fn], acc[fm][fn], 0, 0, 0);
          acc[fm][fn] = __builtin_amdgcn_mfma_f32_16x16x32_bf16(afl[fm], bfh[fn], acc[fm][fn], 0, 0, 0);
          acc[fm][fn] = __builtin_amdgcn_mfma_f32_16x16x32_bf16(afh[fm], bfl[fn], acc[fm][fn], 0, 0, 0);
        }
    }
    __syncthreads();
  }
  // epilogue: D row=(lane>>4)*4+r, col=lane&15 (m89-verified)
  #pragma unroll
  for (int fm = 0; fm < 4; ++fm) {
    int mrow = bm0 + wr * 64 + fm * 16 + kgrp * 4;
    #pragma unroll
    for (int fn = 0; fn < 4; ++fn) {
      int ncol = bn0 + wc * 64 + fn * 16 + lrow;
      #pragma unroll
      for (int r = 0; r < 4; ++r)
        C[(size_t)(mrow + r) * N + ncol] = acc[fm][fn][r];
    }
  }
}

// ---------------- edge aggregation: h = a + y[idx]; max/min over k + channel sums ----------------
__global__ __launch_bounds__(256) void aggregate_kernel(const float* __restrict__ ay,
                                                        const int* __restrict__ idxb, int O,
                                                        float* __restrict__ mx,
                                                        float* __restrict__ mn,
                                                        float* __restrict__ sumsbin) {
  __shared__ float ls[2][256];
  for (int i = threadIdx.x; i < 512; i += 256) ((float*)ls)[i] = 0.f;
  __syncthreads();

  int warp = threadIdx.x >> 6, lane = threadIdx.x & 63;
  int pt = blockIdx.x * 4 + warp;   // 0..8191
  int b = pt >> 10;
  int twoO = 2 * O;
  int U = O >> 6;
  const float* ayrow = ay + (size_t)pt * twoO;

  float av[4], s1[4], s2[4], vmx[4], vmn[4];
  for (int u = 0; u < U; ++u) {
    av[u] = ayrow[u * 64 + lane];
    s1[u] = 0.f; s2[u] = 0.f; vmx[u] = -3.4e38f; vmn[u] = 3.4e38f;
  }
  const int* ip = idxb + pt * KNN_K;
  for (int k = 0; k < KNN_K; ++k) {
    int j = ip[k];
    const float* yrow = ay + (size_t)(b * N_PTS + j) * twoO + O;
    for (int u = 0; u < U; ++u) {
      float v = av[u] + yrow[u * 64 + lane];
      s1[u] += v; s2[u] = fmaf(v, v, s2[u]);
      vmx[u] = fmaxf(vmx[u], v); vmn[u] = fminf(vmn[u], v);
    }
  }
  for (int u = 0; u < U; ++u) {
    int o = u * 64 + lane;
    mx[(size_t)pt * O + o] = vmx[u];
    mn[(size_t)pt * O + o] = vmn[u];
    atomicAdd(&ls[0][o], s1[u]);
    atomicAdd(&ls[1][o], s2[u]);
  }
  __syncthreads();
  int bin = blockIdx.x & 63;
  float* gb = sumsbin + (size_t)bin * 512;
  for (int o = threadIdx.x; o < O; o += 256) {
    atomicAdd(&gb[o], ls[0][o]);
    atomicAdd(&gb[256 + o], ls[1][o]);
  }
}

__global__ __launch_bounds__(256) void reduce_bins(const float* __restrict__ sumsbin,
                                                   float* __restrict__ sums, int O) {
  int o = threadIdx.x;
  if (o >= O) return;
  float a = 0.f, c = 0.f;
  for (int bin = 0; bin < 64; ++bin) {
    a += sumsbin[bin * 512 + o];
    c += sumsbin[bin * 512 + 256 + o];
  }
  sums[o] = a;
  sums[256 + o] = c;
}

// ---------------- finalize edge layer: BN + relu on (max or min depending on sign) ----------------
__global__ __launch_bounds__(256) void finalize_edge(const float* __restrict__ mx,
                                                     const float* __restrict__ mn,
                                                     const float* __restrict__ sums,
                                                     const float* __restrict__ g,
                                                     const float* __restrict__ beta,
                                                     int oshift,
                                                     float* __restrict__ outseg,
                                                     float cnt_inv) {
  int tid = blockIdx.x * 256 + threadIdx.x;
  int pt = tid >> oshift;
  int o = tid & ((1 << oshift) - 1);
  float s1 = sums[o], s2 = sums[256 + o];
  float mean = s1 * cnt_inv;
  float var = s2 * cnt_inv - mean * mean;
  float rstd = rsqrtf(var + BN_EPS);
  float sc = g[o] * rstd;
  float sel = (sc >= 0.f) ? mx[tid] : mn[tid];
  float v = (sel - mean) * sc + beta[o];
  outseg[(size_t)pt * CAT_C + o] = fmaxf(v, 0.f);
}

// ---------------- layer 5 reductions ----------------
__global__ __launch_bounds__(256) void reduce5(const float* __restrict__ h5,
                                               float* __restrict__ h5mx,
                                               float* __restrict__ h5mn,
                                               float* __restrict__ sums5) {
  int oi = threadIdx.x & 63, ng = threadIdx.x >> 6;
  int o = blockIdx.x * 64 + oi;
  int b = blockIdx.y;
  float mx = -3.4e38f, mn = 3.4e38f, s1 = 0.f, s2 = 0.f;
  for (int n = ng; n < N_PTS; n += 4) {
    float v = h5[(size_t)(b * N_PTS + n) * 1024 + o];
    mx = fmaxf(mx, v); mn = fminf(mn, v);
    s1 += v; s2 = fmaf(v, v, s2);
  }
  __shared__ float red[4][4][64];
  red[ng][0][oi] = mx; red[ng][1][oi] = mn; red[ng][2][oi] = s1; red[ng][3][oi] = s2;
  __syncthreads();
  if (ng == 0) {
    #pragma unroll
    for (int gq = 1; gq < 4; ++gq) {
      mx = fmaxf(mx, red[gq][0][oi]);
      mn = fminf(mn, red[gq][1][oi]);
      s1 += red[gq][2][oi];
      s2 += red[gq][3][oi];
    }
    h5mx[b * 1024 + o] = mx;
    h5mn[b * 1024 + o] = mn;
    atomicAdd(&sums5[o], s1);
    atomicAdd(&sums5[1024 + o], s2);
  }
}

__global__ __launch_bounds__(256) void finalize5(const float* __restrict__ h5mx,
                                                 const float* __restrict__ h5mn,
                                                 const float* __restrict__ sums5,
                                                 const float* __restrict__ g,
                                                 const float* __restrict__ beta,
                                                 float* __restrict__ out,
                                                 float cnt_inv) {
  int tid = blockIdx.x * 256 + threadIdx.x;   // 0..8191
  int o = tid & 1023;
  float s1 = sums5[o], s2 = sums5[1024 + o];
  float mean = s1 * cnt_inv;
  float var = s2 * cnt_inv - mean * mean;
  float rstd = rsqrtf(var + BN_EPS);
  float sc = g[o] * rstd;
  float sel = (sc >= 0.f) ? h5mx[tid] : h5mn[tid];
  float v = (sel - mean) * sc + beta[o];
  out[tid] = fmaxf(v, 0.f);
}

extern "C" void kernel_launch(void* const* d_in, const int* in_sizes, int n_in,
                              void* d_out, int out_size, void* d_ws, size_t ws_size,
                              hipStream_t stream) {
  const float* x = (const float*)d_in[0];
  const float* w[5]  = {(const float*)d_in[1], (const float*)d_in[4], (const float*)d_in[7],
                        (const float*)d_in[10], (const float*)d_in[13]};
  const float* gg[5] = {(const float*)d_in[2], (const float*)d_in[5], (const float*)d_in[8],
                        (const float*)d_in[11], (const float*)d_in[14]};
  const float* bb[5] = {(const float*)d_in[3], (const float*)d_in[6], (const float*)d_in[9],
                        (const float*)d_in[12], (const float*)d_in[15]};
  float* out = (float*)d_out;

  float* W = (float*)d_ws;
  size_t off = 0;
  float* feat0   = W + off; off += (size_t)B_SZ * N_PTS * 3;
  float* catbuf  = W + off; off += (size_t)8192 * CAT_C;
  int*   idxbuf  = (int*)(W + off); off += (size_t)8192 * KNN_K;
  float* aybuf   = W + off; off += (size_t)8192 * 1024;   // aliased: distance matrix D / h5
  float* mxbuf   = W + off; off += (size_t)8192 * 256;
  float* mnbuf   = W + off; off += (size_t)8192 * 256;
  float* wcbuf   = W + off; off += (size_t)512 * 1024;
  float* sumsbin = W + off; off += (size_t)64 * 512;
  float* sums    = W + off; off += 512;
  float* sums5   = W + off; off += 2048;
  float* h5mx    = W + off; off += 8192;
  float* h5mn    = W + off; off += 8192;
  float* x2buf   = W + off; off += 8192;

  float* Dbuf = aybuf;

  transpose_x<<<(B_SZ * 3 * N_PTS + 255) / 256, 256, 0, stream>>>(x, feat0);

  const int Cs[4] = {3, 64, 64, 128};
  const int Os[4] = {64, 64, 128, 256};
  const int osh[4] = {6, 6, 7, 8};
  const int segin[4] = {0, 0, 64, 128};
  const int segout[4] = {0, 64, 128, 256};

  for (int l = 0; l < 4; ++l) {
    int C = Cs[l], O = Os[l], twoO = 2 * O;
    const float* featin = (l == 0) ? feat0 : (catbuf + segin[l]);
    int lda = (l == 0) ? 3 : CAT_C;

    xnorm_kernel<<<32, 256, 0, stream>>>(featin, lda, C, x2buf);
    dist_gemm<<<dim3(16, 16, 8), 256, 0, stream>>>(featin, lda, C, x2buf, Dbuf);
    knn_select<<<2048, 256, 0, stream>>>(Dbuf, idxbuf);

    build_wc<<<(C * twoO + 255) / 256, 256, 0, stream>>>(w[l], C, O, wcbuf);
    gemm_kernel<<<dim3(twoO / 64, 8192 / 64), 256, 0, stream>>>(featin, lda, wcbuf, aybuf,
                                                                8192, twoO, C);
    hipMemsetAsync(sumsbin, 0, (size_t)64 * 512 * sizeof(float), stream);
    aggregate_kernel<<<2048, 256, 0, stream>>>(aybuf, idxbuf, O, mxbuf, mnbuf, sumsbin);
    reduce_bins<<<1, 256, 0, stream>>>(sumsbin, sums, O);
    finalize_edge<<<(8192 * O) / 256, 256, 0, stream>>>(mxbuf, mnbuf, sums, gg[l], bb[l],
                                                        osh[l], catbuf + segout[l],
                                                        1.0f / (8192.0f * KNN_K));
  }

  // layer 5: h5 = cat * w5^T via split-bf16 MFMA (~fp32 accuracy), BN over (b,n), relu, max
  gemm_split<<<dim3(1024 / 128, 8192 / 128), 256, 0, stream>>>(catbuf, CAT_C, w[4], 512,
                                                               aybuf, 1024, 512);
  hipMemsetAsync(sums5, 0, 2048 * sizeof(float), stream);
  reduce5<<<dim3(16, 8), 256, 0, stream>>>(aybuf, h5mx, h5mn, sums5);
  finalize5<<<8192 / 256, 256, 0, stream>>>(h5mx, h5mn, sums5, gg[4], bb[4], out,
                                            1.0f / 8192.0f);
}

// Round 5
// 606.441 us; speedup vs baseline: 2.3675x; 1.1217x over previous
//
#include <hip/hip_runtime.h>
#include <cstddef>

#define B_SZ 8
#define N_PTS 1024
#define KNN_K 20
#define CAT_C 512
#define BN_EPS 1e-5f

typedef unsigned short u16;
typedef unsigned int u32;
typedef __bf16 bf16x8 __attribute__((ext_vector_type(8)));
typedef float f32x4 __attribute__((ext_vector_type(4)));

// ---------------- transpose x (B,3,N) -> feat0 (B,N,3) ----------------
__global__ __launch_bounds__(256) void transpose_x(const float* __restrict__ x,
                                                   float* __restrict__ feat0) {
  int t = blockIdx.x * 256 + threadIdx.x;
  if (t >= B_SZ * 3 * N_PTS) return;
  int b = t / (3 * N_PTS);
  int r = t - b * 3 * N_PTS;
  int c = r / N_PTS;
  int n = r - c * N_PTS;
  feat0[((size_t)(b * N_PTS + n)) * 3 + c] = x[t];
}

// ---------------- squared norms per point ----------------
__global__ __launch_bounds__(256) void xnorm_kernel(const float* __restrict__ feat, int lda,
                                                    int C, float* __restrict__ x2) {
  int p = blockIdx.x * 256 + threadIdx.x;
  if (p >= 8192) return;
  const float* r = feat + (size_t)p * lda;
  float s = 0.f;
  if ((C & 3) == 0) {
    for (int c = 0; c < C; c += 4) {
      float4 v = *(const float4*)(r + c);
      s = fmaf(v.x, v.x, s); s = fmaf(v.y, v.y, s);
      s = fmaf(v.z, v.z, s); s = fmaf(v.w, v.w, s);
    }
  } else {
    for (int c = 0; c < C; ++c) s = fmaf(r[c], r[c], s);
  }
  x2[p] = s;
}

// ---------------- distance GEMM: pd[b,n,m] = (2*x_n.x_m - x2n) - x2m (fp32) ----------------
__global__ __launch_bounds__(256) void dist_gemm(const float* __restrict__ feat, int lda, int K,
                                                 const float* __restrict__ x2,
                                                 float* __restrict__ D) {
  int b = blockIdx.z;
  const float* A = feat + (size_t)b * N_PTS * lda;
  const float* x2b = x2 + b * N_PTS;
  __shared__ float As[16][64];
  __shared__ float Bs[16][68];
  int tx = threadIdx.x & 15, ty = threadIdx.x >> 4;
  int bn0 = blockIdx.x * 64, bm0 = blockIdx.y * 64;
  float acc[4][4];
  #pragma unroll
  for (int i = 0; i < 4; ++i)
    #pragma unroll
    for (int j = 0; j < 4; ++j) acc[i][j] = 0.f;

  for (int k0 = 0; k0 < K; k0 += 16) {
    int t = threadIdx.x;
    int m = t >> 2, kb = (t & 3) * 4;
    const float* ap = A + (size_t)(bm0 + m) * lda + k0 + kb;
    #pragma unroll
    for (int i = 0; i < 4; ++i) As[kb + i][m] = (k0 + kb + i < K) ? ap[i] : 0.f;
    const float* bp = A + (size_t)(bn0 + m) * lda + k0 + kb;
    #pragma unroll
    for (int i = 0; i < 4; ++i) Bs[kb + i][m] = (k0 + kb + i < K) ? bp[i] : 0.f;
    __syncthreads();
    #pragma unroll
    for (int k = 0; k < 16; ++k) {
      float a0[4];
      #pragma unroll
      for (int i = 0; i < 4; ++i) a0[i] = As[k][ty * 4 + i];
      float4 bv = *(const float4*)&Bs[k][tx * 4];
      float b0[4] = {bv.x, bv.y, bv.z, bv.w};
      #pragma unroll
      for (int i = 0; i < 4; ++i)
        #pragma unroll
        for (int j = 0; j < 4; ++j) acc[i][j] = fmaf(a0[i], b0[j], acc[i][j]);
    }
    __syncthreads();
  }
  float x2c[4];
  #pragma unroll
  for (int j = 0; j < 4; ++j) x2c[j] = x2b[bn0 + tx * 4 + j];
  #pragma unroll
  for (int i = 0; i < 4; ++i) {
    float x2r = x2b[bm0 + ty * 4 + i];
    float4 v;
    v.x = (2.f * acc[i][0] - x2r) - x2c[0];
    v.y = (2.f * acc[i][1] - x2r) - x2c[1];
    v.z = (2.f * acc[i][2] - x2r) - x2c[2];
    v.w = (2.f * acc[i][3] - x2r) - x2c[3];
    *(float4*)(D + ((size_t)b * N_PTS + bm0 + ty * 4 + i) * 1024 + bn0 + tx * 4) = v;
  }
}

// ---------------- top-20 selection: one wave per row ----------------
__global__ __launch_bounds__(256) void knn_select(const float* __restrict__ D,
                                                  int* __restrict__ idxout) {
  int warp = threadIdx.x >> 6, lane = threadIdx.x & 63;
  int row = blockIdx.x * 4 + warp;    // 0..8191
  const float* drow = D + (size_t)row * 1024;

  float vals[16];
  #pragma unroll
  for (int t4 = 0; t4 < 4; ++t4) {
    float4 dv = *(const float4*)(drow + lane * 16 + t4 * 4);
    vals[t4 * 4 + 0] = dv.x;
    vals[t4 * 4 + 1] = dv.y;
    vals[t4 * 4 + 2] = dv.z;
    vals[t4 * 4 + 3] = dv.w;
  }

  for (int r = 0; r < KNN_K; ++r) {
    float bv = -3.4e38f;
    int bi = 0x7fffffff;
    #pragma unroll
    for (int t = 0; t < 16; ++t) {
      if (vals[t] > bv) { bv = vals[t]; bi = lane * 16 + t; }
    }
    #pragma unroll
    for (int off = 32; off; off >>= 1) {
      float ov = __shfl_xor(bv, off, 64);
      int oi = __shfl_xor(bi, off, 64);
      if (ov > bv || (ov == bv && oi < bi)) { bv = ov; bi = oi; }
    }
    if ((bi >> 4) == lane) vals[bi & 15] = -3.4e38f;
    if (lane == 0) idxout[row * KNN_K + r] = bi;
  }
}

// ---------------- build combined weight Wc (fp32): [w1-w2 | w2], K=C rows x 2O cols ----------------
__global__ __launch_bounds__(256) void build_wc(const float* __restrict__ w, int C, int O,
                                                float* __restrict__ wc) {
  int t = blockIdx.x * 256 + threadIdx.x;
  int twoO = 2 * O;
  if (t >= C * twoO) return;
  int c = t / twoO, j = t - c * twoO;
  float v;
  if (j < O) v = w[j * (2 * C) + c] - w[j * (2 * C) + C + c];
  else       v = w[(j - O) * (2 * C) + C + c];
  wc[t] = v;
}

// ---------------- fp32 GEMM (edge layers): C[M,N] = A[M,K](lda) * B[K,N] ----------------
__global__ __launch_bounds__(256) void gemm_kernel(const float* __restrict__ A, int lda,
                                                   const float* __restrict__ Bm,
                                                   float* __restrict__ Cm,
                                                   int M, int N, int K) {
  __shared__ float As[16][64];
  __shared__ float Bs[16][68];
  int tx = threadIdx.x & 15, ty = threadIdx.x >> 4;
  int bn0 = blockIdx.x * 64, bm0 = blockIdx.y * 64;
  float acc[4][4];
  #pragma unroll
  for (int i = 0; i < 4; ++i)
    #pragma unroll
    for (int j = 0; j < 4; ++j) acc[i][j] = 0.f;

  for (int k0 = 0; k0 < K; k0 += 16) {
    {
      int t = threadIdx.x;
      int m = t >> 2, kb = (t & 3) * 4;
      const float* ap = A + (size_t)(bm0 + m) * lda + k0 + kb;
      #pragma unroll
      for (int i = 0; i < 4; ++i) As[kb + i][m] = (k0 + kb + i < K) ? ap[i] : 0.f;
      int r = t >> 4, c4 = (t & 15) * 4;
      float4 bv = make_float4(0.f, 0.f, 0.f, 0.f);
      if (k0 + r < K) bv = *(const float4*)(Bm + (size_t)(k0 + r) * N + bn0 + c4);
      *(float4*)&Bs[r][c4] = bv;
    }
    __syncthreads();
    #pragma unroll
    for (int k = 0; k < 16; ++k) {
      float a0[4];
      #pragma unroll
      for (int i = 0; i < 4; ++i) a0[i] = As[k][ty * 4 + i];
      float4 bv = *(const float4*)&Bs[k][tx * 4];
      float b0[4] = {bv.x, bv.y, bv.z, bv.w};
      #pragma unroll
      for (int i = 0; i < 4; ++i)
        #pragma unroll
        for (int j = 0; j < 4; ++j) acc[i][j] = fmaf(a0[i], b0[j], acc[i][j]);
    }
    __syncthreads();
  }
  #pragma unroll
  for (int i = 0; i < 4; ++i) {
    float4 v = make_float4(acc[i][0], acc[i][1], acc[i][2], acc[i][3]);
    *(float4*)(Cm + (size_t)(bm0 + ty * 4 + i) * N + bn0 + tx * 4) = v;
  }
}

// ---------------- split fp32 -> bf16 hi/lo MFMA GEMM for layer 5, fused reduction ----------------
// Computes h5 tile = A[M,K] * Bt[N,K]^T (Markidis split, ~fp32 accuracy), then reduces
// max/min/sum/sumsq over the tile's 128 rows per column and writes ONLY partials:
// parts[stat][m_tile][o], stat in {mx,mn,s1,s2}. h5 never touches HBM.
__device__ inline void split8(const float* __restrict__ p, bf16x8* hv, bf16x8* lv) {
  float4 a0 = *(const float4*)p, a1 = *(const float4*)(p + 4);
  float v[8] = {a0.x, a0.y, a0.z, a0.w, a1.x, a1.y, a1.z, a1.w};
  bf16x8 h, l;
  #pragma unroll
  for (int j = 0; j < 8; ++j) {
    __bf16 hj = (__bf16)v[j];
    h[j] = hj;
    l[j] = (__bf16)(v[j] - (float)hj);
  }
  *hv = h; *lv = l;
}

__global__ __launch_bounds__(256) void gemm_split_red(const float* __restrict__ A, int lda,
                                                      const float* __restrict__ Bt, int ldb,
                                                      float* __restrict__ parts, int K) {
  __shared__ u16 Ah[128 * 64];
  __shared__ u16 Al[128 * 64];
  __shared__ u16 Bh[128 * 64];
  __shared__ u16 Bl[128 * 64];
  int tid = threadIdx.x;
  int wave = tid >> 6, lane = tid & 63;
  int wr = wave >> 1, wc = wave & 1;
  int bn0 = blockIdx.x * 128, bm0 = blockIdx.y * 128;
  int lrow = lane & 15;
  int kgrp = lane >> 4;

  f32x4 acc[4][4];
  #pragma unroll
  for (int i = 0; i < 4; ++i)
    #pragma unroll
    for (int j = 0; j < 4; ++j) acc[i][j] = (f32x4){0.f, 0.f, 0.f, 0.f};

  for (int k0 = 0; k0 < K; k0 += 64) {
    #pragma unroll
    for (int i = 0; i < 4; ++i) {
      int chunk = tid + i * 256;        // 0..1023
      int row = chunk >> 3;             // 0..127
      int cc = (chunk & 7) * 8;         // fp32 col 0,8,..,56
      int byte = row * 128 + ((cc * 2) ^ ((row & 7) << 4));
      bf16x8 h, l;
      split8(A + (size_t)(bm0 + row) * lda + k0 + cc, &h, &l);
      *(bf16x8*)((char*)Ah + byte) = h;
      *(bf16x8*)((char*)Al + byte) = l;
      split8(Bt + (size_t)(bn0 + row) * ldb + k0 + cc, &h, &l);
      *(bf16x8*)((char*)Bh + byte) = h;
      *(bf16x8*)((char*)Bl + byte) = l;
    }
    __syncthreads();
    #pragma unroll
    for (int kk = 0; kk < 64; kk += 32) {
      int kb = (kk + kgrp * 8) * 2;
      bf16x8 afh[4], afl[4], bfh[4], bfl[4];
      #pragma unroll
      for (int f = 0; f < 4; ++f) {
        int arow = wr * 64 + f * 16 + lrow;
        int abyte = arow * 128 + (kb ^ ((arow & 7) << 4));
        afh[f] = *(const bf16x8*)((const char*)Ah + abyte);
        afl[f] = *(const bf16x8*)((const char*)Al + abyte);
        int brow = wc * 64 + f * 16 + lrow;
        int bbyte = brow * 128 + (kb ^ ((brow & 7) << 4));
        bfh[f] = *(const bf16x8*)((const char*)Bh + bbyte);
        bfl[f] = *(const bf16x8*)((const char*)Bl + bbyte);
      }
      #pragma unroll
      for (int fm = 0; fm < 4; ++fm)
        #pragma unroll
        for (int fn = 0; fn < 4; ++fn) {
          acc[fm][fn] = __builtin_amdgcn_mfma_f32_16x16x32_bf16(afh[fm], bfh[fn], acc[fm][fn], 0, 0, 0);
          acc[fm][fn] = __builtin_amdgcn_mfma_f32_16x16x32_bf16(afl[fm], bfh[fn], acc[fm][fn], 0, 0, 0);
          acc[fm][fn] = __builtin_amdgcn_mfma_f32_16x16x32_bf16(afh[fm], bfl[fn], acc[fm][fn], 0, 0, 0);
        }
    }
    __syncthreads();
  }

  // ---- fused per-tile reduction over the 128 rows (n within one b) ----
  // thread covers rows wr*64+fm*16+kgrp*4+r, cols wc*64+fn*16+lrow.
  // scratch[contrib(8)][col(128)][stat(4)] = 4096 floats -> reuse Ah (16KB).
  float* scratch = (float*)Ah;
  int contrib = wr * 4 + kgrp;
  #pragma unroll
  for (int fn = 0; fn < 4; ++fn) {
    float mx = -3.4e38f, mn = 3.4e38f, s1 = 0.f, s2 = 0.f;
    #pragma unroll
    for (int fm = 0; fm < 4; ++fm)
      #pragma unroll
      for (int r = 0; r < 4; ++r) {
        float v = acc[fm][fn][r];
        mx = fmaxf(mx, v); mn = fminf(mn, v);
        s1 += v; s2 = fmaf(v, v, s2);
      }
    int col = wc * 64 + fn * 16 + lrow;
    float* sp = scratch + (contrib * 128 + col) * 4;
    sp[0] = mx; sp[1] = mn; sp[2] = s1; sp[3] = s2;
  }
  __syncthreads();
  if (tid < 128) {
    float mx = -3.4e38f, mn = 3.4e38f, s1 = 0.f, s2 = 0.f;
    #pragma unroll
    for (int c2 = 0; c2 < 8; ++c2) {
      const float* sp = scratch + (c2 * 128 + tid) * 4;
      mx = fmaxf(mx, sp[0]); mn = fminf(mn, sp[1]);
      s1 += sp[2]; s2 += sp[3];
    }
    size_t o = (size_t)blockIdx.y * 1024 + bn0 + tid;   // [m_tile][o]
    parts[o] = mx;
    parts[65536 + o] = mn;
    parts[131072 + o] = s1;
    parts[196608 + o] = s2;
  }
}

// ---------------- edge aggregation: h = a + y[idx]; max/min over k + channel sums ----------------
__global__ __launch_bounds__(256) void aggregate_kernel(const float* __restrict__ ay,
                                                        const int* __restrict__ idxb, int O,
                                                        float* __restrict__ mx,
                                                        float* __restrict__ mn,
                                                        float* __restrict__ sumsbin) {
  __shared__ float ls[2][256];
  for (int i = threadIdx.x; i < 512; i += 256) ((float*)ls)[i] = 0.f;
  __syncthreads();

  int warp = threadIdx.x >> 6, lane = threadIdx.x & 63;
  int pt = blockIdx.x * 4 + warp;   // 0..8191
  int b = pt >> 10;
  int twoO = 2 * O;
  int U = O >> 6;
  const float* ayrow = ay + (size_t)pt * twoO;

  float av[4], s1[4], s2[4], vmx[4], vmn[4];
  for (int u = 0; u < U; ++u) {
    av[u] = ayrow[u * 64 + lane];
    s1[u] = 0.f; s2[u] = 0.f; vmx[u] = -3.4e38f; vmn[u] = 3.4e38f;
  }
  const int* ip = idxb + pt * KNN_K;
  for (int k = 0; k < KNN_K; ++k) {
    int j = ip[k];
    const float* yrow = ay + (size_t)(b * N_PTS + j) * twoO + O;
    for (int u = 0; u < U; ++u) {
      float v = av[u] + yrow[u * 64 + lane];
      s1[u] += v; s2[u] = fmaf(v, v, s2[u]);
      vmx[u] = fmaxf(vmx[u], v); vmn[u] = fminf(vmn[u], v);
    }
  }
  for (int u = 0; u < U; ++u) {
    int o = u * 64 + lane;
    mx[(size_t)pt * O + o] = vmx[u];
    mn[(size_t)pt * O + o] = vmn[u];
    atomicAdd(&ls[0][o], s1[u]);
    atomicAdd(&ls[1][o], s2[u]);
  }
  __syncthreads();
  int bin = blockIdx.x & 63;
  float* gb = sumsbin + (size_t)bin * 512;
  for (int o = threadIdx.x; o < O; o += 256) {
    atomicAdd(&gb[o], ls[0][o]);
    atomicAdd(&gb[256 + o], ls[1][o]);
  }
}

__global__ __launch_bounds__(256) void reduce_bins(const float* __restrict__ sumsbin,
                                                   float* __restrict__ sums, int O) {
  int o = threadIdx.x;
  if (o >= O) return;
  float a = 0.f, c = 0.f;
  for (int bin = 0; bin < 64; ++bin) {
    a += sumsbin[bin * 512 + o];
    c += sumsbin[bin * 512 + 256 + o];
  }
  sums[o] = a;
  sums[256 + o] = c;
}

// ---------------- finalize edge layer: BN + relu on (max or min depending on sign) ----------------
__global__ __launch_bounds__(256) void finalize_edge(const float* __restrict__ mx,
                                                     const float* __restrict__ mn,
                                                     const float* __restrict__ sums,
                                                     const float* __restrict__ g,
                                                     const float* __restrict__ beta,
                                                     int oshift,
                                                     float* __restrict__ outseg,
                                                     float cnt_inv) {
  int tid = blockIdx.x * 256 + threadIdx.x;
  int pt = tid >> oshift;
  int o = tid & ((1 << oshift) - 1);
  float s1 = sums[o], s2 = sums[256 + o];
  float mean = s1 * cnt_inv;
  float var = s2 * cnt_inv - mean * mean;
  float rstd = rsqrtf(var + BN_EPS);
  float sc = g[o] * rstd;
  float sel = (sc >= 0.f) ? mx[tid] : mn[tid];
  float v = (sel - mean) * sc + beta[o];
  outseg[(size_t)pt * CAT_C + o] = fmaxf(v, 0.f);
}

// ---------------- layer 5 finalize from tile partials ----------------
__global__ __launch_bounds__(256) void finalize5_fused(const float* __restrict__ parts,
                                                       const float* __restrict__ g,
                                                       const float* __restrict__ beta,
                                                       float* __restrict__ out) {
  int tid = blockIdx.x * 256 + threadIdx.x;   // 0..8191
  int b = tid >> 10, o = tid & 1023;
  const float* pmx = parts;
  const float* pmn = parts + 65536;
  const float* ps1 = parts + 131072;
  const float* ps2 = parts + 196608;
  float s1 = 0.f, s2 = 0.f;
  for (int t = 0; t < 64; ++t) { s1 += ps1[t * 1024 + o]; s2 += ps2[t * 1024 + o]; }
  float mx = -3.4e38f, mn = 3.4e38f;
  #pragma unroll
  for (int t = 0; t < 8; ++t) {
    mx = fmaxf(mx, pmx[(b * 8 + t) * 1024 + o]);
    mn = fminf(mn, pmn[(b * 8 + t) * 1024 + o]);
  }
  float mean = s1 * (1.0f / 8192.0f);
  float var = s2 * (1.0f / 8192.0f) - mean * mean;
  float rstd = rsqrtf(var + BN_EPS);
  float sc = g[o] * rstd;
  float sel = (sc >= 0.f) ? mx : mn;
  float v = (sel - mean) * sc + beta[o];
  out[tid] = fmaxf(v, 0.f);
}

extern "C" void kernel_launch(void* const* d_in, const int* in_sizes, int n_in,
                              void* d_out, int out_size, void* d_ws, size_t ws_size,
                              hipStream_t stream) {
  const float* x = (const float*)d_in[0];
  const float* w[5]  = {(const float*)d_in[1], (const float*)d_in[4], (const float*)d_in[7],
                        (const float*)d_in[10], (const float*)d_in[13]};
  const float* gg[5] = {(const float*)d_in[2], (const float*)d_in[5], (const float*)d_in[8],
                        (const float*)d_in[11], (const float*)d_in[14]};
  const float* bb[5] = {(const float*)d_in[3], (const float*)d_in[6], (const float*)d_in[9],
                        (const float*)d_in[12], (const float*)d_in[15]};
  float* out = (float*)d_out;

  float* W = (float*)d_ws;
  size_t off = 0;
  float* feat0   = W + off; off += (size_t)B_SZ * N_PTS * 3;
  float* catbuf  = W + off; off += (size_t)8192 * CAT_C;
  int*   idxbuf  = (int*)(W + off); off += (size_t)8192 * KNN_K;
  float* aybuf   = W + off; off += (size_t)8192 * 1024;   // aliased: distance matrix D
  float* mxbuf   = W + off; off += (size_t)8192 * 256;
  float* mnbuf   = W + off; off += (size_t)8192 * 256;
  float* wcbuf   = W + off; off += (size_t)512 * 1024;
  float* sumsbin = W + off; off += (size_t)64 * 512;
  float* sums    = W + off; off += 512;
  float* parts   = W + off; off += (size_t)4 * 64 * 1024;  // L5 tile partials (mx,mn,s1,s2)
  float* x2buf   = W + off; off += 8192;

  float* Dbuf = aybuf;

  transpose_x<<<(B_SZ * 3 * N_PTS + 255) / 256, 256, 0, stream>>>(x, feat0);

  const int Cs[4] = {3, 64, 64, 128};
  const int Os[4] = {64, 64, 128, 256};
  const int osh[4] = {6, 6, 7, 8};
  const int segin[4] = {0, 0, 64, 128};
  const int segout[4] = {0, 64, 128, 256};

  for (int l = 0; l < 4; ++l) {
    int C = Cs[l], O = Os[l], twoO = 2 * O;
    const float* featin = (l == 0) ? feat0 : (catbuf + segin[l]);
    int lda = (l == 0) ? 3 : CAT_C;

    xnorm_kernel<<<32, 256, 0, stream>>>(featin, lda, C, x2buf);
    dist_gemm<<<dim3(16, 16, 8), 256, 0, stream>>>(featin, lda, C, x2buf, Dbuf);
    knn_select<<<2048, 256, 0, stream>>>(Dbuf, idxbuf);

    build_wc<<<(C * twoO + 255) / 256, 256, 0, stream>>>(w[l], C, O, wcbuf);
    gemm_kernel<<<dim3(twoO / 64, 8192 / 64), 256, 0, stream>>>(featin, lda, wcbuf, aybuf,
                                                                8192, twoO, C);
    hipMemsetAsync(sumsbin, 0, (size_t)64 * 512 * sizeof(float), stream);
    aggregate_kernel<<<2048, 256, 0, stream>>>(aybuf, idxbuf, O, mxbuf, mnbuf, sumsbin);
    reduce_bins<<<1, 256, 0, stream>>>(sumsbin, sums, O);
    finalize_edge<<<(8192 * O) / 256, 256, 0, stream>>>(mxbuf, mnbuf, sums, gg[l], bb[l],
                                                        osh[l], catbuf + segout[l],
                                                        1.0f / (8192.0f * KNN_K));
  }

  // layer 5: h5 = cat * w5^T via split-bf16 MFMA with fused per-tile reduction (no h5 in HBM)
  gemm_split_red<<<dim3(1024 / 128, 8192 / 128), 256, 0, stream>>>(catbuf, CAT_C, w[4], 512,
                                                                   parts, 512);
  finalize5_fused<<<8192 / 256, 256, 0, stream>>>(parts, gg[4], bb[4], out);
}